// Round 4
// baseline (692.631 us; speedup 1.0000x reference)
//
#include <hip/hip_runtime.h>
#include <hip/hip_bf16.h>
#include <stdint.h>

// Problem: T=128, B=32, D=1024, H=1024 LSTM unroll, fp32 in/out.
#define T_STEPS 128
#define BATCH   32
#define DIM     1024
#define HID     1024
#define NGATE   4096            // 4*H
#define MROWS   4096            // T*B
#define NWGR    64              // persistent recurrence workgroups (16 units each)

typedef unsigned int u32;
typedef __attribute__((ext_vector_type(8)))  __bf16 bf16x8;
typedef __attribute__((ext_vector_type(4)))  float  f32x4;
typedef __attribute__((ext_vector_type(16))) float  f32x16;
typedef __attribute__((ext_vector_type(4)))  u32    u32x4;

__device__ __forceinline__ unsigned short f2bf(float f) {
    u32 x = __float_as_uint(f);
    return (unsigned short)((x + 0x7fffu + ((x >> 16) & 1u)) >> 16);  // RNE
}
__device__ __forceinline__ float sigf(float x) {
    return 1.0f / (1.0f + __expf(-x));
}
__device__ __forceinline__ float tanh_fast(float x) {
    float ax = fabsf(x);
    float e  = __expf(-2.0f * ax);           // in (0,1], no overflow
    float t  = (1.0f - e) / (1.0f + e);
    return copysignf(t, x);
}
__device__ __forceinline__ u32 umax2(u32 a, u32 b) { return a > b ? a : b; }

// DEVICE-scope (agent) store: sc1 only. Bypasses L1 + per-XCD L2, served by
// the memory-side Infinity Cache. hb is ONLY touched through sc1 ops during
// lstm_rec -> no line of it ever lives in any L2 -> no fences needed.
__device__ __forceinline__ void store_u32_coh(u32* p, u32 v) {
    asm volatile("global_store_dword %0, %1, off sc1" :: "v"(p), "v"(v) : "memory");
}

// ---------------- prep kernels ----------------

__global__ void cast_f32_bf16(const float* __restrict__ in,
                              unsigned short* __restrict__ out, int n) {
    int idx = (blockIdx.x * blockDim.x + threadIdx.x) * 4;
    if (idx + 3 < n) {
        float4 v = *(const float4*)(in + idx);
        ushort4 o;
        o.x = f2bf(v.x); o.y = f2bf(v.y); o.z = f2bf(v.z); o.w = f2bf(v.w);
        *(ushort4*)(out + idx) = o;
    }
}

// sentinel fill: 0xFFFFFFFF = packed (NaN|NaN) bf16 pair; h is always finite
// and in (-1,1), so a real packed h can never equal the sentinel.
__global__ void fill_sentinel(u32* __restrict__ p, int n) {
    int i = (blockIdx.x * blockDim.x + threadIdx.x) * 4;
    if (i + 3 < n) {
        u32x4 v = {0xFFFFFFFFu, 0xFFFFFFFFu, 0xFFFFFFFFu, 0xFFFFFFFFu};
        *(u32x4*)(p + i) = v;
    }
}

// in: R x C fp32 (row-major) -> out: C x R bf16 (row-major transpose)
__global__ void transpose_cast(const float* __restrict__ in,
                               unsigned short* __restrict__ out, int R, int C) {
    __shared__ float tile[32][33];
    int c0 = blockIdx.x * 32, r0 = blockIdx.y * 32;
    int tx = threadIdx.x, ty = threadIdx.y;     // 32 x 8
#pragma unroll
    for (int i = 0; i < 4; ++i)
        tile[ty + i * 8][tx] = in[(size_t)(r0 + ty + i * 8) * C + c0 + tx];
    __syncthreads();
#pragma unroll
    for (int i = 0; i < 4; ++i)
        out[(size_t)(c0 + ty + i * 8) * R + r0 + tx] = f2bf(tile[tx][ty + i * 8]);
}

// ---------------- phase 1: Gp = perm(x @ Wx + b)  (bf16 MFMA, fp32 out) ----------------
// A: MROWS x DIM bf16 (x), BT: NGATE x DIM bf16 (WxT).
// Output in GATE-MINOR panels for the 64-WG recurrence:
//   orig col co = g*1024 + hu  ->  panel wg = hu>>4 (16 units), local unit u = hu&15,
//   panel col cp = u*4 + g  (so 4 gates of a unit are CONTIGUOUS -> f32x4 epilogue)
//   Gp[((size_t)wg*MROWS + row)*64 + cp]
__global__ __launch_bounds__(256) void gemm_xw(
    const unsigned short* __restrict__ A,
    const unsigned short* __restrict__ BT,
    const float* __restrict__ bias,
    float* __restrict__ Gp) {
    __shared__ unsigned short As[128 * 32];
    __shared__ unsigned short Bs[128 * 32];
    int tid  = threadIdx.x;
    int wave = tid >> 6, lane = tid & 63;
    int q = lane >> 4, c = lane & 15;
    int wm = wave >> 1, wn = wave & 1;
    int tm = blockIdx.y * 128, tn = blockIdx.x * 128;

    f32x4 acc[4][4] = {};

    const int srow0 = tid >> 2;           // 0..63
    const int srow1 = 64 + (tid >> 2);    // 64..127
    const int scol  = (tid & 3) * 8;      // bf16 elems

    u32x4 ra0, ra1, rb0, rb1;
    ra0 = *(const u32x4*)(A  + (size_t)(tm + srow0) * DIM + scol);
    ra1 = *(const u32x4*)(A  + (size_t)(tm + srow1) * DIM + scol);
    rb0 = *(const u32x4*)(BT + (size_t)(tn + srow0) * DIM + scol);
    rb1 = *(const u32x4*)(BT + (size_t)(tn + srow1) * DIM + scol);

    for (int kk = 0; kk < 32; ++kk) {
        __syncthreads();
        *(u32x4*)(As + srow0 * 32 + scol) = ra0;
        *(u32x4*)(As + srow1 * 32 + scol) = ra1;
        *(u32x4*)(Bs + srow0 * 32 + scol) = rb0;
        *(u32x4*)(Bs + srow1 * 32 + scol) = rb1;
        __syncthreads();
        if (kk < 31) {
            int ko = (kk + 1) * 32 + scol;
            ra0 = *(const u32x4*)(A  + (size_t)(tm + srow0) * DIM + ko);
            ra1 = *(const u32x4*)(A  + (size_t)(tm + srow1) * DIM + ko);
            rb0 = *(const u32x4*)(BT + (size_t)(tn + srow0) * DIM + ko);
            rb1 = *(const u32x4*)(BT + (size_t)(tn + srow1) * DIM + ko);
        }
        bf16x8 af[4], bfv[4];
#pragma unroll
        for (int i = 0; i < 4; ++i) {
            af[i]  = *(const bf16x8*)(As + (wm * 64 + i * 16 + c) * 32 + q * 8);
            bfv[i] = *(const bf16x8*)(Bs + (wn * 64 + i * 16 + c) * 32 + q * 8);
        }
#pragma unroll
        for (int i = 0; i < 4; ++i)
#pragma unroll
            for (int j = 0; j < 4; ++j)
                acc[i][j] = __builtin_amdgcn_mfma_f32_16x16x32_bf16(
                    af[i], bfv[j], acc[i][j], 0, 0, 0);
    }
    // epilogue: C/D layout col = lane&15, row = quad*4 + reg; gate-minor store
#pragma unroll
    for (int j = 0; j < 4; ++j) {
        int co = tn + wn * 64 + j * 16 + c;
        float bj = bias[co];
        int g = co >> 10, hu = co & 1023;
        int wgr = hu >> 4, u = hu & 15;
        int cp = u * 4 + g;
#pragma unroll
        for (int i = 0; i < 4; ++i) {
            int row0 = tm + wm * 64 + i * 16 + q * 4;
#pragma unroll
            for (int r = 0; r < 4; ++r)
                Gp[((size_t)wgr * MROWS + row0 + r) * 64 + cp] = acc[i][j][r] + bj;
        }
    }
}

// ---------------- phase 2: persistent recurrence ----------------
// 64 WGs x 512 threads (8 waves). WG wg owns 16 hidden units -> 64 gate-minor
// panel cols (2 MFMA col-tiles of 32). Wave wv = K-EIGHTH; each A-fragment
// read feeds BOTH col-tiles (zero A redundancy).
//
// R4 changes (drain theory): the poll's vmcnt(0) was waiting on HBM-latency
// stragglers issued at the end of the previous step -- the Gp prefetch and
// the out-store (~900cy acks) -- stretching poll round 1 past h-readiness
// and inviting stale-sample retries. Our OWN h-store ack in the drain is
// free (global h-readiness >= our store visibility).
//  1. Gp prefetch double-buffered + issued right after barrier A -> a full
//     step of slack, never in the drain.
//  2. out-stores batched x4 via shift register (static indices), flushed
//     every 4th step -> HBM ack in 1 of 4 polls.
//  3. h pack via __shfl_xor (adjacent lanes) instead of the Ht LDS bounce ->
//     h-store issues ~150cy earlier (helps every consumer).
// Sentinel protocol, slab staging, Hs XOR-swizzle unchanged from R2/R3.
__global__ __launch_bounds__(512, 1) void lstm_rec(
    const unsigned short* __restrict__ WhT,   // NGATE x DIM bf16
    const float* __restrict__ Gp,             // gate-minor panels, 64 x 4096 x 64 fp32
    unsigned short* hb,                       // (T+1) x BATCH x HID bf16 (slot 0 unused)
    float* __restrict__ out) {                // T x BATCH x HID fp32
    __shared__ unsigned short Hs[32][1024];   // h tile, XOR-swizzled rows (64 KB)
    __shared__ float SlT[8][32][64];          // K-eighth partials [ks][b][panel col] (64 KB)
    const int wg = blockIdx.x, tid = threadIdx.x;
    const int wv = tid >> 6, lane = tid & 63;
    const int ln = lane & 31, lh = lane >> 5;

    // ---- stage B-fragments (Wh) into registers, once ----
    // B-frag (32x32x16): col = lane&31 = u8*4+g (gate-minor), k = wv*128 + kk*16 + lh*8 + j
    bf16x8 br0[8], br1[8];
    {
        const int u8 = ln >> 2, g = ln & 3;
        const unsigned short* w0 =
            WhT + (size_t)(g * HID + wg * 16 + 0 * 8 + u8) * DIM + wv * 128 + lh * 8;
        const unsigned short* w1 =
            WhT + (size_t)(g * HID + wg * 16 + 1 * 8 + u8) * DIM + wv * 128 + lh * 8;
#pragma unroll
        for (int kk = 0; kk < 8; ++kk) {
            br0[kk] = *(const bf16x8*)(w0 + kk * 16);
            br1[kk] = *(const bf16x8*)(w1 + kk * 16);
        }
    }

    // epilogue mapping: thread = (batch, u); ONE output per thread
    const int batch = tid >> 4, uu = tid & 15;
    float cs = 0.f;
    // G prefetch for t=0 (gate-minor: f32x4 = 4 gates of unit uu)
    f32x4 ga = *(const f32x4*)(Gp + ((size_t)wg * MROWS + batch) * 64 + uu * 4);

    // out-store shift register (static indices -- rule #20)
    float o0 = 0.f, o1 = 0.f, o2 = 0.f, o3 = 0.f;

    char* hs_base = (char*)&Hs[0][0];
    const int rxor = (ln & 15) << 4;          // read-side swizzle constant

    for (int t = 0; t < T_STEPS; ++t) {
        f32x4 gan;
        if (t > 0) {
            // ---- coalesced, sentinel-validated h load (wave-local retry) ----
            // flat byte layout of slot t: batch*2048 + unit*2 (row-major).
            // wave wv owns bytes [wv*8K, wv*8K+8K): 8 instrs x 1KB contiguous.
            const char* p0 = (const char*)hb + ((size_t)t << 16)
                           + ((size_t)wv << 13) + (size_t)lane * 16;
            const char* p1 = p0 + 4096;
            u32x4 h[8];
            for (;;) {
                asm volatile(
                    "global_load_dwordx4 %0, %8, off sc1\n\t"
                    "global_load_dwordx4 %1, %8, off offset:1024 sc1\n\t"
                    "global_load_dwordx4 %2, %8, off offset:2048 sc1\n\t"
                    "global_load_dwordx4 %3, %8, off offset:3072 sc1\n\t"
                    "global_load_dwordx4 %4, %9, off sc1\n\t"
                    "global_load_dwordx4 %5, %9, off offset:1024 sc1\n\t"
                    "global_load_dwordx4 %6, %9, off offset:2048 sc1\n\t"
                    "global_load_dwordx4 %7, %9, off offset:3072 sc1\n\t"
                    "s_waitcnt vmcnt(0)"
                    : "=&v"(h[0]), "=&v"(h[1]), "=&v"(h[2]), "=&v"(h[3]),
                      "=&v"(h[4]), "=&v"(h[5]), "=&v"(h[6]), "=&v"(h[7])
                    : "v"(p0), "v"(p1)
                    : "memory");
                u32 m = 0;
#pragma unroll
                for (int i = 0; i < 8; ++i) {
                    u32 a = umax2(umax2(h[i][0], h[i][1]),
                                  umax2(h[i][2], h[i][3]));
                    m = umax2(m, a);
                }
                if (!__any((int)(m == 0xFFFFFFFFu))) break;
            }
            // ---- stage into swizzled LDS (R2 formula, unchanged) ----
#pragma unroll
            for (int j = 0; j < 8; ++j) {
                int row  = (wv << 2) + (j >> 1);
                int colb = ((j & 1) << 10) + lane * 16;
                int off  = (row << 11) + (colb ^ ((row & 15) << 4));
                *(u32x4*)(hs_base + off) = h[j];
            }
            asm volatile("s_waitcnt lgkmcnt(0)" ::: "memory");
            __builtin_amdgcn_s_barrier();            // barrier A: Hs ready

            // ---- early G prefetch for t+1 (in flight across MFMA+epilogue+poll) ----
            {
                const int tnx = (t + 1 < T_STEPS) ? t + 1 : t;
                gan = *(const f32x4*)(Gp + ((size_t)wg * MROWS + (size_t)tnx * 32 + batch) * 64
                                      + uu * 4);
            }

            // ---- K-eighth: 8 A-reads, 16 MFMAs (each read feeds BOTH tiles) ----
            // A-frag (32x32x16): row = lane&31 (batch), k = wv*128 + kk*16 + lh*8 + j
            f32x16 acc0 = {}, acc1 = {};
            const char* hrow = hs_base + (ln << 11);
#pragma unroll
            for (int kk = 0; kk < 8; ++kk) {
                int cb = ((wv << 8) + (kk << 5) + (lh << 4)) ^ rxor;
                bf16x8 a = *(const bf16x8*)(hrow + cb);
                acc0 = __builtin_amdgcn_mfma_f32_32x32x16_bf16(a, br0[kk], acc0, 0, 0, 0);
                acc1 = __builtin_amdgcn_mfma_f32_32x32x16_bf16(a, br1[kk], acc1, 0, 0, 0);
            }

            // ---- dump partials: SlT[ks][b][col], banks = ln -> conflict-free ----
            // C layout 32x32: col = lane&31, b = (reg&3) + 8*(reg>>2) + 4*(lane>>5)
#pragma unroll
            for (int rg = 0; rg < 4; ++rg)
#pragma unroll
                for (int rr = 0; rr < 4; ++rr) {
                    const int bb = rg * 8 + lh * 4 + rr;
                    SlT[wv][bb][ln]      = acc0[rg * 4 + rr];
                    SlT[wv][bb][32 + ln] = acc1[rg * 4 + rr];
                }
            asm volatile("s_waitcnt lgkmcnt(0)" ::: "memory");
            __builtin_amdgcn_s_barrier();            // barrier B: SlT ready
        } else {
            gan = *(const f32x4*)(Gp + ((size_t)wg * MROWS + 32 + batch) * 64 + uu * 4);
        }

        // ---- epilogue: ONE output (batch, unit uu) per thread ----
        f32x4 gv = ga;                               // gates i,f,g,o of unit uu
        if (t > 0) {
#pragma unroll
            for (int ks = 0; ks < 8; ++ks)
                gv += *(const f32x4*)&SlT[ks][batch][uu * 4];
        }
        float cn = sigf(gv[1]) * cs + sigf(gv[0]) * tanh_fast(gv[2]);
        cs = cn;
        float hv = sigf(gv[3]) * tanh_fast(cn);

        // pack h pairs via lane shuffle (pairs are adjacent lanes) and publish
        // IMMEDIATELY -- earliest possible h visibility for all consumers.
        u32 hw = (u32)f2bf(hv);
        u32 pw = (u32)__shfl_xor((int)hw, 1, 64);
        if ((lane & 1) == 0) {
            store_u32_coh((u32*)(hb + (size_t)(t + 1) * (BATCH * HID)
                                    + (size_t)batch * HID + wg * 16 + uu), hw | (pw << 16));
        }

        // off the critical path: batched out-store (flush every 4th step ->
        // HBM store-ack appears in only 1 of 4 poll drains)
        o0 = o1; o1 = o2; o2 = o3; o3 = hv;
        if ((t & 3) == 3) {
            const size_t ob = (size_t)batch * HID + wg * 16 + uu;
            out[(size_t)(t - 3) * (BATCH * HID) + ob] = o0;
            out[(size_t)(t - 2) * (BATCH * HID) + ob] = o1;
            out[(size_t)(t - 1) * (BATCH * HID) + ob] = o2;
            out[(size_t)(t    ) * (BATCH * HID) + ob] = o3;
        }
        ga = gan;
        // no end-of-loop barrier: stage(t+1) Hs writes are sentinel-gated behind
        // every wave's h-store(t+1), which follows its SlT/Hs reads of step t.
    }
}

// ---------------- launch ----------------

extern "C" void kernel_launch(void* const* d_in, const int* in_sizes, int n_in,
                              void* d_out, int out_size, void* d_ws, size_t ws_size,
                              hipStream_t stream) {
    const float* x  = (const float*)d_in[0];   // T*B*D
    const float* Wx = (const float*)d_in[1];   // D x 4H
    const float* Wh = (const float*)d_in[2];   // H x 4H
    const float* b  = (const float*)d_in[3];   // 4H
    float* out = (float*)d_out;

    // workspace layout (bytes)
    char* ws = (char*)d_ws;
    const size_t OFF_XBF  = 0;                       // 8 MB  (4096x1024 bf16)
    const size_t OFF_WXT  = 8ull  << 20;             // 8 MB  (4096x1024 bf16)
    const size_t OFF_WHT  = 16ull << 20;             // 8 MB  (4096x1024 bf16)
    const size_t OFF_G    = 24ull << 20;             // 64 MB (64x4096x64 fp32 gate-minor)
    const size_t OFF_HB   = 88ull << 20;             // 129 * 64 KB = 8.0625 MB
    const size_t NEEDED   = OFF_HB + (size_t)(T_STEPS + 1) * BATCH * HID * 2;
    if (ws_size < NEEDED) return;  // loud failure (output stays poisoned)

    unsigned short* xbf = (unsigned short*)(ws + OFF_XBF);
    unsigned short* WxT = (unsigned short*)(ws + OFF_WXT);
    unsigned short* WhT = (unsigned short*)(ws + OFF_WHT);
    float*          Gp  = (float*)(ws + OFF_G);
    unsigned short* hb  = (unsigned short*)(ws + OFF_HB);

    // prep
    cast_f32_bf16<<<(MROWS * DIM / 4 + 255) / 256, 256, 0, stream>>>(x, xbf, MROWS * DIM);
    const int HBW = (T_STEPS + 1) * BATCH * HID / 2;    // u32 words in hb
    fill_sentinel<<<(HBW / 4 + 255) / 256, 256, 0, stream>>>((u32*)hb, HBW);
    dim3 tb(32, 8);
    transpose_cast<<<dim3(NGATE / 32, DIM / 32), tb, 0, stream>>>(Wx, WxT, DIM, NGATE);
    transpose_cast<<<dim3(NGATE / 32, HID / 32), tb, 0, stream>>>(Wh, WhT, HID, NGATE);

    // phase 1: all-timestep input GEMM (gate-minor permuted output)
    gemm_xw<<<dim3(NGATE / 128, MROWS / 128), 256, 0, stream>>>(xbf, WxT, b, Gp);

    // phase 2: persistent recurrence
    lstm_rec<<<NWGR, 512, 0, stream>>>(WhT, Gp, hb, out);
}

// Round 5
// 525.405 us; speedup vs baseline: 1.3183x; 1.3183x over previous
//
#include <hip/hip_runtime.h>
#include <hip/hip_bf16.h>
#include <stdint.h>

// Problem: T=128, B=32, D=1024, H=1024 LSTM unroll, fp32 in/out.
#define T_STEPS 128
#define BATCH   32
#define DIM     1024
#define HID     1024
#define NGATE   4096            // 4*H
#define MROWS   4096            // T*B
#define NWGR    64              // persistent recurrence workgroups (16 units each)

typedef unsigned int u32;
typedef __attribute__((ext_vector_type(8)))  __bf16 bf16x8;
typedef __attribute__((ext_vector_type(4)))  float  f32x4;
typedef __attribute__((ext_vector_type(16))) float  f32x16;
typedef __attribute__((ext_vector_type(4)))  u32    u32x4;

__device__ __forceinline__ unsigned short f2bf(float f) {
    u32 x = __float_as_uint(f);
    return (unsigned short)((x + 0x7fffu + ((x >> 16) & 1u)) >> 16);  // RNE
}
__device__ __forceinline__ float sigf(float x) {
    return 1.0f / (1.0f + __expf(-x));
}
__device__ __forceinline__ float tanh_fast(float x) {
    float ax = fabsf(x);
    float e  = __expf(-2.0f * ax);           // in (0,1], no overflow
    float t  = (1.0f - e) / (1.0f + e);
    return copysignf(t, x);
}
__device__ __forceinline__ u32 umax2(u32 a, u32 b) { return a > b ? a : b; }

// DEVICE-scope (agent) store: sc1 only. Bypasses L1 + per-XCD L2, served by
// the memory-side Infinity Cache. hb is ONLY touched through sc1 ops during
// lstm_rec -> no line of it ever lives in any L2 -> no fences needed.
__device__ __forceinline__ void store_u32_coh(u32* p, u32 v) {
    asm volatile("global_store_dword %0, %1, off sc1" :: "v"(p), "v"(v) : "memory");
}

// ---------------- prep kernels ----------------

__global__ void cast_f32_bf16(const float* __restrict__ in,
                              unsigned short* __restrict__ out, int n) {
    int idx = (blockIdx.x * blockDim.x + threadIdx.x) * 4;
    if (idx + 3 < n) {
        float4 v = *(const float4*)(in + idx);
        ushort4 o;
        o.x = f2bf(v.x); o.y = f2bf(v.y); o.z = f2bf(v.z); o.w = f2bf(v.w);
        *(ushort4*)(out + idx) = o;
    }
}

// sentinel fill: 0xFFFFFFFF = packed (NaN|NaN) bf16 pair; h is always finite
// and in (-1,1), so a real packed h can never equal the sentinel.
__global__ void fill_sentinel(u32* __restrict__ p, int n) {
    int i = (blockIdx.x * blockDim.x + threadIdx.x) * 4;
    if (i + 3 < n) {
        u32x4 v = {0xFFFFFFFFu, 0xFFFFFFFFu, 0xFFFFFFFFu, 0xFFFFFFFFu};
        *(u32x4*)(p + i) = v;
    }
}

// in: R x C fp32 (row-major) -> out: C x R bf16 (row-major transpose)
__global__ void transpose_cast(const float* __restrict__ in,
                               unsigned short* __restrict__ out, int R, int C) {
    __shared__ float tile[32][33];
    int c0 = blockIdx.x * 32, r0 = blockIdx.y * 32;
    int tx = threadIdx.x, ty = threadIdx.y;     // 32 x 8
#pragma unroll
    for (int i = 0; i < 4; ++i)
        tile[ty + i * 8][tx] = in[(size_t)(r0 + ty + i * 8) * C + c0 + tx];
    __syncthreads();
#pragma unroll
    for (int i = 0; i < 4; ++i)
        out[(size_t)(c0 + ty + i * 8) * R + r0 + tx] = f2bf(tile[tx][ty + i * 8]);
}

// ---------------- phase 1: Gp = perm(x @ Wx + b)  (bf16 MFMA, fp32 out) ----------------
// A: MROWS x DIM bf16 (x), BT: NGATE x DIM bf16 (WxT).
// Output in GATE-MINOR panels for the 64-WG recurrence:
//   orig col co = g*1024 + hu  ->  panel wg = hu>>4 (16 units), local unit u = hu&15,
//   panel col cp = u*4 + g  (so 4 gates of a unit are CONTIGUOUS -> f32x4 epilogue)
//   Gp[((size_t)wg*MROWS + row)*64 + cp]
__global__ __launch_bounds__(256) void gemm_xw(
    const unsigned short* __restrict__ A,
    const unsigned short* __restrict__ BT,
    const float* __restrict__ bias,
    float* __restrict__ Gp) {
    __shared__ unsigned short As[128 * 32];
    __shared__ unsigned short Bs[128 * 32];
    int tid  = threadIdx.x;
    int wave = tid >> 6, lane = tid & 63;
    int q = lane >> 4, c = lane & 15;
    int wm = wave >> 1, wn = wave & 1;
    int tm = blockIdx.y * 128, tn = blockIdx.x * 128;

    f32x4 acc[4][4] = {};

    const int srow0 = tid >> 2;           // 0..63
    const int srow1 = 64 + (tid >> 2);    // 64..127
    const int scol  = (tid & 3) * 8;      // bf16 elems

    u32x4 ra0, ra1, rb0, rb1;
    ra0 = *(const u32x4*)(A  + (size_t)(tm + srow0) * DIM + scol);
    ra1 = *(const u32x4*)(A  + (size_t)(tm + srow1) * DIM + scol);
    rb0 = *(const u32x4*)(BT + (size_t)(tn + srow0) * DIM + scol);
    rb1 = *(const u32x4*)(BT + (size_t)(tn + srow1) * DIM + scol);

    for (int kk = 0; kk < 32; ++kk) {
        __syncthreads();
        *(u32x4*)(As + srow0 * 32 + scol) = ra0;
        *(u32x4*)(As + srow1 * 32 + scol) = ra1;
        *(u32x4*)(Bs + srow0 * 32 + scol) = rb0;
        *(u32x4*)(Bs + srow1 * 32 + scol) = rb1;
        __syncthreads();
        if (kk < 31) {
            int ko = (kk + 1) * 32 + scol;
            ra0 = *(const u32x4*)(A  + (size_t)(tm + srow0) * DIM + ko);
            ra1 = *(const u32x4*)(A  + (size_t)(tm + srow1) * DIM + ko);
            rb0 = *(const u32x4*)(BT + (size_t)(tn + srow0) * DIM + ko);
            rb1 = *(const u32x4*)(BT + (size_t)(tn + srow1) * DIM + ko);
        }
        bf16x8 af[4], bfv[4];
#pragma unroll
        for (int i = 0; i < 4; ++i) {
            af[i]  = *(const bf16x8*)(As + (wm * 64 + i * 16 + c) * 32 + q * 8);
            bfv[i] = *(const bf16x8*)(Bs + (wn * 64 + i * 16 + c) * 32 + q * 8);
        }
#pragma unroll
        for (int i = 0; i < 4; ++i)
#pragma unroll
            for (int j = 0; j < 4; ++j)
                acc[i][j] = __builtin_amdgcn_mfma_f32_16x16x32_bf16(
                    af[i], bfv[j], acc[i][j], 0, 0, 0);
    }
    // epilogue: C/D layout col = lane&15, row = quad*4 + reg; gate-minor store
#pragma unroll
    for (int j = 0; j < 4; ++j) {
        int co = tn + wn * 64 + j * 16 + c;
        float bj = bias[co];
        int g = co >> 10, hu = co & 1023;
        int wgr = hu >> 4, u = hu & 15;
        int cp = u * 4 + g;
#pragma unroll
        for (int i = 0; i < 4; ++i) {
            int row0 = tm + wm * 64 + i * 16 + q * 4;
#pragma unroll
            for (int r = 0; r < 4; ++r)
                Gp[((size_t)wgr * MROWS + row0 + r) * 64 + cp] = acc[i][j][r] + bj;
        }
    }
}

// ---------------- phase 2: persistent recurrence ----------------
// 64 WGs x 512 threads (8 waves). WG wg owns 16 hidden units -> 64 gate-minor
// panel cols (2 MFMA col-tiles of 32). Wave wv = K-EIGHTH; each A-fragment
// read feeds BOTH col-tiles (zero A redundancy). Structure = R3 (330us).
//
// R5 (drain surgery; R4 postmortem): any HIP-level load consumed after an
// asm-volatile-with-memory block gets a conservative s_waitcnt vmcnt(0) at
// its use -- so ALL waits must be positioned where the poll's own vmcnt(0)
// already makes them free. Invariant: the only vmem op younger than ~1500cy
// at poll entry is our h-store (IC ack ~400cy, hidden under the ~600cy load
// latency). Concretely:
//  1. out-store of step t-1's hv issues POST-poll(t) -> its HBM ack (~900cy)
//     completes in the ~1800cy shadow before the next vmcnt(0).
//  2. Gp prefetch (gan, slice t+1) issues POST-poll(t); consumed at the TOP
//     of epilogue(t+1) (~1500cy later) -> its conservative wait is ~free.
//  3. h pack via __shfl_xor (adjacent lanes), publish immediately.
// Sentinel protocol, slab staging, Hs XOR-swizzle unchanged from R2/R3.
__global__ __launch_bounds__(512, 1) void lstm_rec(
    const unsigned short* __restrict__ WhT,   // NGATE x DIM bf16
    const float* __restrict__ Gp,             // gate-minor panels, 64 x 4096 x 64 fp32
    unsigned short* hb,                       // (T+1) x BATCH x HID bf16 (slot 0 unused)
    float* __restrict__ out) {                // T x BATCH x HID fp32
    __shared__ unsigned short Hs[32][1024];   // h tile, XOR-swizzled rows (64 KB)
    __shared__ float SlT[8][32][64];          // K-eighth partials [ks][b][panel col] (64 KB)
    const int wg = blockIdx.x, tid = threadIdx.x;
    const int wv = tid >> 6, lane = tid & 63;
    const int ln = lane & 31, lh = lane >> 5;

    // ---- stage B-fragments (Wh) into registers, once ----
    // B-frag (32x32x16): col = lane&31 = u8*4+g (gate-minor), k = wv*128 + kk*16 + lh*8 + j
    bf16x8 br0[8], br1[8];
    {
        const int u8 = ln >> 2, g = ln & 3;
        const unsigned short* w0 =
            WhT + (size_t)(g * HID + wg * 16 + 0 * 8 + u8) * DIM + wv * 128 + lh * 8;
        const unsigned short* w1 =
            WhT + (size_t)(g * HID + wg * 16 + 1 * 8 + u8) * DIM + wv * 128 + lh * 8;
#pragma unroll
        for (int kk = 0; kk < 8; ++kk) {
            br0[kk] = *(const bf16x8*)(w0 + kk * 16);
            br1[kk] = *(const bf16x8*)(w1 + kk * 16);
        }
    }

    // epilogue mapping: thread = (batch, u); ONE output per thread
    const int batch = tid >> 4, uu = tid & 15;
    const size_t ob = (size_t)batch * HID + wg * 16 + uu;   // out column index
    float cs = 0.f;
    float hvprev = 0.f;                        // out-store deferred one step
    // G prefetch for t=0 (gate-minor: f32x4 = 4 gates of unit uu)
    f32x4 ga = *(const f32x4*)(Gp + ((size_t)wg * MROWS + batch) * 64 + uu * 4);

    char* hs_base = (char*)&Hs[0][0];
    const int rxor = (ln & 15) << 4;          // read-side swizzle constant

    for (int t = 0; t < T_STEPS; ++t) {
        f32x4 gan;
        if (t > 0) {
            // ---- coalesced, sentinel-validated h load (wave-local retry) ----
            // flat byte layout of slot t: batch*2048 + unit*2 (row-major).
            // wave wv owns bytes [wv*8K, wv*8K+8K): 8 instrs x 1KB contiguous.
            // vmcnt(0) here drains ONLY our h-store's IC ack (~400cy), hidden
            // under the ~600cy load latency -- everything else is >1500cy old.
            const char* p0 = (const char*)hb + ((size_t)t << 16)
                           + ((size_t)wv << 13) + (size_t)lane * 16;
            const char* p1 = p0 + 4096;
            u32x4 h[8];
            for (;;) {
                asm volatile(
                    "global_load_dwordx4 %0, %8, off sc1\n\t"
                    "global_load_dwordx4 %1, %8, off offset:1024 sc1\n\t"
                    "global_load_dwordx4 %2, %8, off offset:2048 sc1\n\t"
                    "global_load_dwordx4 %3, %8, off offset:3072 sc1\n\t"
                    "global_load_dwordx4 %4, %9, off sc1\n\t"
                    "global_load_dwordx4 %5, %9, off offset:1024 sc1\n\t"
                    "global_load_dwordx4 %6, %9, off offset:2048 sc1\n\t"
                    "global_load_dwordx4 %7, %9, off offset:3072 sc1\n\t"
                    "s_waitcnt vmcnt(0)"
                    : "=&v"(h[0]), "=&v"(h[1]), "=&v"(h[2]), "=&v"(h[3]),
                      "=&v"(h[4]), "=&v"(h[5]), "=&v"(h[6]), "=&v"(h[7])
                    : "v"(p0), "v"(p1)
                    : "memory");
                u32 m = 0;
#pragma unroll
                for (int i = 0; i < 8; ++i) {
                    u32 a = umax2(umax2(h[i][0], h[i][1]),
                                  umax2(h[i][2], h[i][3]));
                    m = umax2(m, a);
                }
                if (!__any((int)(m == 0xFFFFFFFFu))) break;
            }

            // ---- POST-poll, off-drain issues (acks complete in the shadow) ----
            out[((size_t)(t - 1) * BATCH) * HID + ob] = hvprev;   // step t-1 output
            gan = *(const f32x4*)(Gp + ((size_t)wg * MROWS
                    + (size_t)((t + 1 < T_STEPS) ? t + 1 : t) * 32 + batch) * 64 + uu * 4);

            // ---- stage into swizzled LDS (R2 formula, unchanged) ----
#pragma unroll
            for (int j = 0; j < 8; ++j) {
                int row  = (wv << 2) + (j >> 1);
                int colb = ((j & 1) << 10) + lane * 16;
                int off  = (row << 11) + (colb ^ ((row & 15) << 4));
                *(u32x4*)(hs_base + off) = h[j];
            }
            asm volatile("s_waitcnt lgkmcnt(0)" ::: "memory");
            __builtin_amdgcn_s_barrier();            // barrier A: Hs ready

            // ---- K-eighth: 8 A-reads, 16 MFMAs (each read feeds BOTH tiles) ----
            // A-frag (32x32x16): row = lane&31 (batch), k = wv*128 + kk*16 + lh*8 + j
            f32x16 acc0 = {}, acc1 = {};
            const char* hrow = hs_base + (ln << 11);
#pragma unroll
            for (int kk = 0; kk < 8; ++kk) {
                int cb = ((wv << 8) + (kk << 5) + (lh << 4)) ^ rxor;
                bf16x8 a = *(const bf16x8*)(hrow + cb);
                acc0 = __builtin_amdgcn_mfma_f32_32x32x16_bf16(a, br0[kk], acc0, 0, 0, 0);
                acc1 = __builtin_amdgcn_mfma_f32_32x32x16_bf16(a, br1[kk], acc1, 0, 0, 0);
            }

            // ---- dump partials: SlT[ks][b][col], banks = ln -> conflict-free ----
            // C layout 32x32: col = lane&31, b = (reg&3) + 8*(reg>>2) + 4*(lane>>5)
#pragma unroll
            for (int rg = 0; rg < 4; ++rg)
#pragma unroll
                for (int rr = 0; rr < 4; ++rr) {
                    const int bb = rg * 8 + lh * 4 + rr;
                    SlT[wv][bb][ln]      = acc0[rg * 4 + rr];
                    SlT[wv][bb][32 + ln] = acc1[rg * 4 + rr];
                }
            asm volatile("s_waitcnt lgkmcnt(0)" ::: "memory");
            __builtin_amdgcn_s_barrier();            // barrier B: SlT ready
        } else {
            gan = *(const f32x4*)(Gp + ((size_t)wg * MROWS + 32 + batch) * 64 + uu * 4);
        }

        // ---- epilogue: ONE output (batch, unit uu) per thread ----
        f32x4 gv = ga;                               // gates i,f,g,o of unit uu
        ga = gan;      // rotate EARLY: gan is ~1500cy old -> conservative wait ~free
        if (t > 0) {
#pragma unroll
            for (int ks = 0; ks < 8; ++ks)
                gv += *(const f32x4*)&SlT[ks][batch][uu * 4];
        }
        float cn = sigf(gv[1]) * cs + sigf(gv[0]) * tanh_fast(gv[2]);
        cs = cn;
        float hv = sigf(gv[3]) * tanh_fast(cn);

        // pack h pairs via lane shuffle (pairs are adjacent lanes) and publish
        // IMMEDIATELY -- earliest possible h visibility for all consumers.
        u32 hw = (u32)f2bf(hv);
        u32 pw = (u32)__shfl_xor((int)hw, 1, 64);
        if ((lane & 1) == 0) {
            store_u32_coh((u32*)(hb + (size_t)(t + 1) * (BATCH * HID)
                                    + (size_t)batch * HID + wg * 16 + uu), hw | (pw << 16));
        }
        hvprev = hv;                                 // out-store happens post-poll(t+1)
        // no end-of-loop barrier: stage(t+1) Hs writes are sentinel-gated behind
        // every wave's h-store(t+1), which follows its SlT/Hs reads of step t.
    }
    // final deferred output (step T-1)
    out[((size_t)(T_STEPS - 1) * BATCH) * HID + ob] = hvprev;
}

// ---------------- launch ----------------

extern "C" void kernel_launch(void* const* d_in, const int* in_sizes, int n_in,
                              void* d_out, int out_size, void* d_ws, size_t ws_size,
                              hipStream_t stream) {
    const float* x  = (const float*)d_in[0];   // T*B*D
    const float* Wx = (const float*)d_in[1];   // D x 4H
    const float* Wh = (const float*)d_in[2];   // H x 4H
    const float* b  = (const float*)d_in[3];   // 4H
    float* out = (float*)d_out;

    // workspace layout (bytes)
    char* ws = (char*)d_ws;
    const size_t OFF_XBF  = 0;                       // 8 MB  (4096x1024 bf16)
    const size_t OFF_WXT  = 8ull  << 20;             // 8 MB  (4096x1024 bf16)
    const size_t OFF_WHT  = 16ull << 20;             // 8 MB  (4096x1024 bf16)
    const size_t OFF_G    = 24ull << 20;             // 64 MB (64x4096x64 fp32 gate-minor)
    const size_t OFF_HB   = 88ull << 20;             // 129 * 64 KB = 8.0625 MB
    const size_t NEEDED   = OFF_HB + (size_t)(T_STEPS + 1) * BATCH * HID * 2;
    if (ws_size < NEEDED) return;  // loud failure (output stays poisoned)

    unsigned short* xbf = (unsigned short*)(ws + OFF_XBF);
    unsigned short* WxT = (unsigned short*)(ws + OFF_WXT);
    unsigned short* WhT = (unsigned short*)(ws + OFF_WHT);
    float*          Gp  = (float*)(ws + OFF_G);
    unsigned short* hb  = (unsigned short*)(ws + OFF_HB);

    // prep
    cast_f32_bf16<<<(MROWS * DIM / 4 + 255) / 256, 256, 0, stream>>>(x, xbf, MROWS * DIM);
    const int HBW = (T_STEPS + 1) * BATCH * HID / 2;    // u32 words in hb
    fill_sentinel<<<(HBW / 4 + 255) / 256, 256, 0, stream>>>((u32*)hb, HBW);
    dim3 tb(32, 8);
    transpose_cast<<<dim3(NGATE / 32, DIM / 32), tb, 0, stream>>>(Wx, WxT, DIM, NGATE);
    transpose_cast<<<dim3(NGATE / 32, HID / 32), tb, 0, stream>>>(Wh, WhT, HID, NGATE);

    // phase 1: all-timestep input GEMM (gate-minor permuted output)
    gemm_xw<<<dim3(NGATE / 128, MROWS / 128), 256, 0, stream>>>(xbf, WxT, b, Gp);

    // phase 2: persistent recurrence
    lstm_rec<<<NWGR, 512, 0, stream>>>(WhT, Gp, hb, out);
}